// Round 7
// baseline (49.622 us; speedup 1.0000x reference)
//
#include <hip/hip_runtime.h>
#include <hip/hip_bf16.h>
#include <math.h>

#define B_ROWS 4096
#define N_ROWS 8192
#define D_DIM  128
// (1/T) * log2(e) = 2 * 1.4426950408889634
#define SCALE_LOG2 2.8853900817779268f
// sqrt(SCALE_LOG2): folded into row normalization so MFMA output is already
// in log2 domain
#define PRESCALE 1.6986436f
// ln2/4: converts the 4x-duplicated group-dot back to the label logit 2*cos
#define LN2_OVER_4 0.17328679513998632f

#define RSPLIT 64                      // 128-row blocks
#define CSPLIT 64                      // 128-col blocks

typedef __bf16 bf16x8 __attribute__((ext_vector_type(8)));
typedef __bf16 bf16x2 __attribute__((ext_vector_type(2)));
typedef float  f32x16 __attribute__((ext_vector_type(16)));

#if __has_builtin(__builtin_amdgcn_exp2f)
#define EXP2F(x) __builtin_amdgcn_exp2f(x)
#else
#define EXP2F(x) exp2f(x)
#endif

#define AS(n) __attribute__((address_space(n)))

// Packed fragment-major layout (16B chunk units):
//   chunk(p, kk, l) = zn[p*32 + (l&31)][ (kk*2 + (l>>5))*8 .. +8 ]   (8 bf16)
//   addr16B = p*512 + kk*64 + l
// one wave MFMA-fragment load = 64 consecutive 16B chunks = 1KB coalesced.

// ---------- K1: normalize rows of concat(z_i, z_j) -> packed bf16 ----------
__global__ __launch_bounds__(256) void k_normalize(const float* __restrict__ zi,
                                                   const float* __restrict__ zj,
                                                   __bf16* __restrict__ pack) {
    const int wid  = threadIdx.x >> 6;
    const int lane = threadIdx.x & 63;
    const int row  = blockIdx.x * 4 + wid;
    const float* src = (row < B_ROWS) ? (zi + (size_t)row * D_DIM)
                                      : (zj + (size_t)(row - B_ROWS) * D_DIM);
    float2 v = ((const float2*)src)[lane];
    float ss = v.x * v.x + v.y * v.y;
    #pragma unroll
    for (int off = 1; off < 64; off <<= 1) ss += __shfl_xor(ss, off, 64);
    float inv = PRESCALE / fmaxf(sqrtf(ss), 1e-8f);
    bf16x2 o;
    o[0] = (__bf16)(v.x * inv);
    o[1] = (__bf16)(v.y * inv);
    // elements e = 2*lane, 2*lane+1 -> kk = lane>>3, h = (lane>>2)&1, m = lane&3
    const int chunk = ((row >> 5) << 9) + ((lane >> 3) << 6) +
                      (((lane >> 2) & 1) << 5) + (row & 31);
    ((bf16x2*)pack)[chunk * 4 + (lane & 3)] = o;
}

// ---------- K2: NT-GEMM (zn . zn^T) with fused exp2 row-sum ----------
// 128x128 output tile per block (grid 64x64). Phase structure is the fix:
//   1. async-stage the 32KB B panel (4 packed col-panels) into LDS via
//      global_load_lds (no VGPR round-trip); A frags load concurrently.
//   2. ONE barrier.
//   3. 4 independent col-tile chains: {8 ds_read_b128, 8 MFMA, 16 exp2} --
//      ~32 MFMA + 64 exp2 of uninterrupted compute, ds_reads of chain c+1
//      pipelined under MFMAs of chain c (counted lgkmcnt, compiler-emitted).
// Cross-block overlap: 4 blocks/CU resident (32KB LDS, VGPR<=128); block
// n+1 stages while block n computes. No per-tile barriers anywhere.
__global__ __launch_bounds__(256, 4) void k_gemm_expsum(const __bf16* __restrict__ pack,
                                                        float* __restrict__ partials) {
    const int rb   = blockIdx.x;   // 0..63 row-block (128 rows)
    const int cs   = blockIdx.y;   // 0..63 col-block (128 cols)
    const int wid  = threadIdx.x >> 6;
    const int lane = threadIdx.x & 63;
    const int h    = lane >> 5;    // lane half (k-group)
    const int ln   = lane & 31;

    __shared__ __bf16 Bs[16384];   // 32 KB = 4 col-panels x 512 chunks x 16B

    const bf16x8* pk = (const bf16x8*)pack;   // 16B chunk units

    // 1a. async-stage B panel: packed panels [4cs, 4cs+3] -> LDS, linear.
    // wave wid stages chunks q*256 + wid*64 + lane (wave-uniform LDS base).
    {
        const size_t gbase = (size_t)cs * 2048;
        #pragma unroll
        for (int q = 0; q < 8; ++q) {
            const int cidx = q * 256 + wid * 64;   // wave-uniform chunk index
            __builtin_amdgcn_global_load_lds(
                (const AS(1) void*)(pk + gbase + cidx + lane),
                (AS(3) void*)(Bs + (size_t)cidx * 8), 16, 0, 0);
        }
    }

    // 1b. A fragments (private, coalesced) - in flight during B staging
    const int row0 = rb * 128 + wid * 32;
    const size_t pa = (size_t)(row0 >> 5) * 512;
    bf16x8 a[8];
    #pragma unroll
    for (int kk = 0; kk < 8; ++kk)
        a[kk] = pk[pa + kk * 64 + lane];

    float sums[16];
    #pragma unroll
    for (int i = 0; i < 16; ++i) sums[i] = 0.0f;

    // 2. one barrier (drains vmcnt: global_load_lds + A loads)
    __syncthreads();

    // 3. four independent col-tile compute chains
    const bf16x8* bs8 = (const bf16x8*)Bs;
    #pragma unroll
    for (int c = 0; c < 4; ++c) {
        f32x16 acc = {};
        #pragma unroll
        for (int kk = 0; kk < 8; ++kk) {
            bf16x8 b = bs8[c * 512 + kk * 64 + lane];   // stride-1 ds_read_b128
            acc = __builtin_amdgcn_mfma_f32_32x32x16_bf16(a[kk], b, acc, 0, 0, 0);
        }
        // rows pre-scaled: acc = logit*log2e, bounded by +-2.89 -> plain exp2
        #pragma unroll
        for (int i = 0; i < 16; ++i)
            sums[i] += EXP2F(acc[i]);   // acc[i] row depends only on (i,h):
                                        // same 16 sums accumulate all 4 chains
    }

    // reduce each row's sum across the 32 lanes of its half (cols), then the
    // lane whose ln == i writes that row's partial. partials row-major
    // [N_ROWS][CSPLIT] so K3 reads coalesce.
    #pragma unroll
    for (int i = 0; i < 16; ++i) {
        float s = sums[i];
        #pragma unroll
        for (int off = 1; off < 32; off <<= 1) s += __shfl_xor(s, off, 64);
        if (ln == i) {
            const int rloc = (i & 3) + 8 * (i >> 2) + 4 * h;  // measured C layout
            partials[(size_t)(row0 + rloc) * CSPLIT + cs] = s;
        }
    }
}

// ---------- K3: merge partials + label logit + nll -> loss ----------
// grid 256 x 4 waves; each wave owns 8 rows. Per row: coalesced 256B partial
// read (64 lanes = 64 cs entries) + 4x-duplicated 16-group label dot.
__global__ __launch_bounds__(256) void k_finalize(const __bf16* __restrict__ pack,
                                                  const float* __restrict__ partials,
                                                  float* __restrict__ out) {
    const int wid  = threadIdx.x >> 6;
    const int lane = threadIdx.x & 63;
    const int rowbase = blockIdx.x * 32 + wid * 8;
    const bf16x8* pk = (const bf16x8*)pack;

    const int g = lane & 15;
    const int goff = ((g >> 1) << 6) + ((g & 1) << 5);

    float accv = 0.0f;
    #pragma unroll
    for (int it = 0; it < 8; ++it) {
        const int r = rowbase + it;
        const int c = (r < B_ROWS) ? r : r - B_ROWS;   // label column
        float p = partials[(size_t)r * CSPLIT + lane];
        bf16x8 av = pk[(size_t)(r >> 5) * 512 + goff + (r & 31)];
        bf16x8 bv = pk[(size_t)(c >> 5) * 512 + goff + (c & 31)];
        float d = 0.0f;
        #pragma unroll
        for (int e = 0; e < 8; ++e) d += (float)av[e] * (float)bv[e];
        // 64-lane reduce: p -> row exp-sum; d -> 4 * SCALE_LOG2 * cos(r,c)
        #pragma unroll
        for (int off = 1; off < 64; off <<= 1) {
            d += __shfl_xor(d, off, 64);
            p += __shfl_xor(p, off, 64);
        }
        if (lane == 0) {
            // nll = ln(sum) - 2*cos = logf(p) - d * ln2/4
            accv += logf(p) - d * LN2_OVER_4;
        }
    }
    __shared__ float ls[4];
    if (lane == 0) ls[wid] = accv;
    __syncthreads();
    if (threadIdx.x == 0) {
        atomicAdd(out, (ls[0] + ls[1] + ls[2] + ls[3]) * (1.0f / (float)N_ROWS));
    }
}

extern "C" void kernel_launch(void* const* d_in, const int* in_sizes, int n_in,
                              void* d_out, int out_size, void* d_ws, size_t ws_size,
                              hipStream_t stream) {
    const float* zi = (const float*)d_in[0];
    const float* zj = (const float*)d_in[1];
    float* out = (float*)d_out;

    __bf16* pack     = (__bf16*)d_ws;                                      // 2 MB
    float*  partials = (float*)((char*)d_ws + (size_t)N_ROWS * D_DIM * 2); // 2 MB

    hipMemsetAsync(out, 0, sizeof(float), stream);
    k_normalize<<<dim3(N_ROWS / 4), dim3(256), 0, stream>>>(zi, zj, pack);
    k_gemm_expsum<<<dim3(RSPLIT, CSPLIT), dim3(256), 0, stream>>>(pack, partials);
    k_finalize<<<dim3(N_ROWS / 32), dim3(256), 0, stream>>>(pack, partials, out);
}

// Round 8
// 45.003 us; speedup vs baseline: 1.1026x; 1.1026x over previous
//
#include <hip/hip_runtime.h>
#include <hip/hip_bf16.h>
#include <math.h>

#define B_ROWS 4096
#define N_ROWS 8192
#define D_DIM  128
// (1/T) * log2(e) = 2 * 1.4426950408889634
#define SCALE_LOG2 2.8853900817779268f
// sqrt(SCALE_LOG2): folded into row normalization so MFMA output is already
// in log2 domain
#define PRESCALE 1.6986436f
// ln2/4: converts the 4x-duplicated group-dot back to the label logit 2*cos
#define LN2_OVER_4 0.17328679513998632f

#define RSPLIT 64                      // 128-row blocks
#define CSPLIT 64                      // 128-col blocks

typedef __bf16 bf16x8 __attribute__((ext_vector_type(8)));
typedef __bf16 bf16x2 __attribute__((ext_vector_type(2)));
typedef float  f32x16 __attribute__((ext_vector_type(16)));

#if __has_builtin(__builtin_amdgcn_exp2f)
#define EXP2F(x) __builtin_amdgcn_exp2f(x)
#else
#define EXP2F(x) exp2f(x)
#endif

#define AS(n) __attribute__((address_space(n)))

// Packed fragment-major layout (16B chunk units):
//   chunk(p, kk, l) = zn[p*32 + (l&31)][ (kk*2 + (l>>5))*8 .. +8 ]   (8 bf16)
//   addr16B = p*512 + kk*64 + l
// one wave MFMA-fragment load = 64 consecutive 16B chunks = 1KB coalesced.

// ---------- K1: normalize rows of concat(z_i, z_j) -> packed bf16 ----------
__global__ __launch_bounds__(256) void k_normalize(const float* __restrict__ zi,
                                                   const float* __restrict__ zj,
                                                   __bf16* __restrict__ pack) {
    const int wid  = threadIdx.x >> 6;
    const int lane = threadIdx.x & 63;
    const int row  = blockIdx.x * 4 + wid;
    const float* src = (row < B_ROWS) ? (zi + (size_t)row * D_DIM)
                                      : (zj + (size_t)(row - B_ROWS) * D_DIM);
    float2 v = ((const float2*)src)[lane];
    float ss = v.x * v.x + v.y * v.y;
    #pragma unroll
    for (int off = 1; off < 64; off <<= 1) ss += __shfl_xor(ss, off, 64);
    float inv = PRESCALE / fmaxf(sqrtf(ss), 1e-8f);
    bf16x2 o;
    o[0] = (__bf16)(v.x * inv);
    o[1] = (__bf16)(v.y * inv);
    // elements e = 2*lane, 2*lane+1 -> kk = lane>>3, h = (lane>>2)&1, m = lane&3
    const int chunk = ((row >> 5) << 9) + ((lane >> 3) << 6) +
                      (((lane >> 2) & 1) << 5) + (row & 31);
    ((bf16x2*)pack)[chunk * 4 + (lane & 3)] = o;
}

// ---------- K2: UPPER-TRIANGLE NT-GEMM with symmetric exp accumulation ----
// logits are symmetric: each off-diagonal 128x128 block (rb < cs) provides
//   - row-sums for its 128 rows (standard C-layout shuffle-reduce, slot cs)
//   - col-sums for its 128 cols (per-lane scalar chain + shfl(32) + LDS
//     combine across the 4 waves, written to slot rb of the COLUMN rows)
// Slot partition per row r in 128-block g: col-path fills [0,g), row-path
// fills [g,64) -- disjoint & complete, so K3 is unchanged.
// Diagonal blocks (rb==cs) do the full 128x128 with row-path only.
// Blocks with cs<rb exit immediately (dynamic backfill rebalances CUs).
// Work halves: 2080/4096 blocks of MFMA + exp + B-traffic.
__global__ __launch_bounds__(256, 4) void k_gemm_expsum(const __bf16* __restrict__ pack,
                                                        float* __restrict__ partials) {
    const int rb = blockIdx.x;     // 0..63 row-block (128 rows)
    const int cs = blockIdx.y;     // 0..63 col-block (128 cols)
    if (cs < rb) return;           // lower triangle: covered by symmetry

    const int wid  = threadIdx.x >> 6;
    const int lane = threadIdx.x & 63;
    const int h    = lane >> 5;    // lane half (k-group)
    const int ln   = lane & 31;

    __shared__ __bf16 Bs[16384];   // 32 KB = 4 col-panels x 512 chunks x 16B
    __shared__ float  cls[4][128]; // per-wave column sums

    const bf16x8* pk = (const bf16x8*)pack;   // 16B chunk units

    // 1a. async-stage B panel: packed panels [4cs, 4cs+3] -> LDS, linear.
    {
        const size_t gbase = (size_t)cs * 2048;
        #pragma unroll
        for (int q = 0; q < 8; ++q) {
            const int cidx = q * 256 + wid * 64;   // wave-uniform chunk index
            __builtin_amdgcn_global_load_lds(
                (const AS(1) void*)(pk + gbase + cidx + lane),
                (AS(3) void*)(Bs + (size_t)cidx * 8), 16, 0, 0);
        }
    }

    // 1b. A fragments (private, coalesced) - in flight during B staging
    const int row0 = rb * 128 + wid * 32;
    const size_t pa = (size_t)(row0 >> 5) * 512;
    bf16x8 a[8];
    #pragma unroll
    for (int kk = 0; kk < 8; ++kk)
        a[kk] = pk[pa + kk * 64 + lane];

    float sums[16];
    #pragma unroll
    for (int i = 0; i < 16; ++i) sums[i] = 0.0f;
    float csum0 = 0.0f, csum1 = 0.0f, csum2 = 0.0f, csum3 = 0.0f;

    // 2. one barrier (drains vmcnt: global_load_lds + A loads)
    __syncthreads();

    // 3. four independent col-tile compute chains
    const bf16x8* bs8 = (const bf16x8*)Bs;
    #pragma unroll
    for (int c = 0; c < 4; ++c) {
        f32x16 acc = {};
        #pragma unroll
        for (int kk = 0; kk < 8; ++kk) {
            bf16x8 b = bs8[c * 512 + kk * 64 + lane];   // stride-1 ds_read_b128
            acc = __builtin_amdgcn_mfma_f32_32x32x16_bf16(a[kk], b, acc, 0, 0, 0);
        }
        // rows pre-scaled: acc = logit*log2e, bounded by +-2.89 -> plain exp2
        float cacc = 0.0f;
        #pragma unroll
        for (int i = 0; i < 16; ++i) {
            float e = EXP2F(acc[i]);
            sums[i] += e;       // row-sum accumulation (col-reduced later)
            cacc    += e;       // this lane's column (c*32+ln) partial
        }
        if (c == 0) csum0 += cacc;
        else if (c == 1) csum1 += cacc;
        else if (c == 2) csum2 += cacc;
        else csum3 += cacc;
    }

    // row-path: reduce across the 32 col-lanes, write slot cs
    #pragma unroll
    for (int i = 0; i < 16; ++i) {
        float s = sums[i];
        #pragma unroll
        for (int off = 1; off < 32; off <<= 1) s += __shfl_xor(s, off, 64);
        if (ln == i) {
            const int rloc = (i & 3) + 8 * (i >> 2) + 4 * h;  // measured C layout
            partials[(size_t)(row0 + rloc) * CSPLIT + cs] = s;
        }
    }

    // col-path (off-diagonal only): combine h-halves, then the 4 waves via
    // LDS, write slot rb of the column rows.
    csum0 += __shfl_xor(csum0, 32, 64);
    csum1 += __shfl_xor(csum1, 32, 64);
    csum2 += __shfl_xor(csum2, 32, 64);
    csum3 += __shfl_xor(csum3, 32, 64);
    if (h == 0) {
        cls[wid][ln]      = csum0;
        cls[wid][32 + ln] = csum1;
        cls[wid][64 + ln] = csum2;
        cls[wid][96 + ln] = csum3;
    }
    __syncthreads();
    if (cs > rb && threadIdx.x < 128) {
        const int t = threadIdx.x;
        float v = cls[0][t] + cls[1][t] + cls[2][t] + cls[3][t];
        partials[(size_t)(cs * 128 + t) * CSPLIT + rb] = v;
    }
}

// ---------- K3: merge partials + label logit + nll -> loss ----------
// grid 256 x 4 waves; each wave owns 8 rows. Per row: coalesced 256B partial
// read (64 lanes = 64 slots) + 4x-duplicated 16-group label dot.
__global__ __launch_bounds__(256) void k_finalize(const __bf16* __restrict__ pack,
                                                  const float* __restrict__ partials,
                                                  float* __restrict__ out) {
    const int wid  = threadIdx.x >> 6;
    const int lane = threadIdx.x & 63;
    const int rowbase = blockIdx.x * 32 + wid * 8;
    const bf16x8* pk = (const bf16x8*)pack;

    const int g = lane & 15;
    const int goff = ((g >> 1) << 6) + ((g & 1) << 5);

    float accv = 0.0f;
    #pragma unroll
    for (int it = 0; it < 8; ++it) {
        const int r = rowbase + it;
        const int c = (r < B_ROWS) ? r : r - B_ROWS;   // label column
        float p = partials[(size_t)r * CSPLIT + lane];
        bf16x8 av = pk[(size_t)(r >> 5) * 512 + goff + (r & 31)];
        bf16x8 bv = pk[(size_t)(c >> 5) * 512 + goff + (c & 31)];
        float d = 0.0f;
        #pragma unroll
        for (int e = 0; e < 8; ++e) d += (float)av[e] * (float)bv[e];
        // 64-lane reduce: p -> row exp-sum; d -> 4 * SCALE_LOG2 * cos(r,c)
        #pragma unroll
        for (int off = 1; off < 64; off <<= 1) {
            d += __shfl_xor(d, off, 64);
            p += __shfl_xor(p, off, 64);
        }
        if (lane == 0) {
            // nll = ln(sum) - 2*cos = logf(p) - d * ln2/4
            accv += logf(p) - d * LN2_OVER_4;
        }
    }
    __shared__ float ls[4];
    if (lane == 0) ls[wid] = accv;
    __syncthreads();
    if (threadIdx.x == 0) {
        atomicAdd(out, (ls[0] + ls[1] + ls[2] + ls[3]) * (1.0f / (float)N_ROWS));
    }
}

extern "C" void kernel_launch(void* const* d_in, const int* in_sizes, int n_in,
                              void* d_out, int out_size, void* d_ws, size_t ws_size,
                              hipStream_t stream) {
    const float* zi = (const float*)d_in[0];
    const float* zj = (const float*)d_in[1];
    float* out = (float*)d_out;

    __bf16* pack     = (__bf16*)d_ws;                                      // 2 MB
    float*  partials = (float*)((char*)d_ws + (size_t)N_ROWS * D_DIM * 2); // 2 MB

    hipMemsetAsync(out, 0, sizeof(float), stream);
    k_normalize<<<dim3(N_ROWS / 4), dim3(256), 0, stream>>>(zi, zj, pack);
    k_gemm_expsum<<<dim3(RSPLIT, CSPLIT), dim3(256), 0, stream>>>(pack, partials);
    k_finalize<<<dim3(N_ROWS / 32), dim3(256), 0, stream>>>(pack, partials, out);
}